// Round 23
// baseline (98.910 us; speedup 1.0000x reference)
//
#include <hip/hip_runtime.h>
#include <hip/hip_bf16.h>
#include <stdint.h>

#define HID 1024
#define NH 16
#define HD 64
#define SEQ 2048
#define BATCH 2
#define M_TOT 4096
#define QSCALE 0.18033688011112042f  /* 0.125 * log2(e) */

typedef __attribute__((ext_vector_type(8))) short short8;
typedef __attribute__((ext_vector_type(4))) float f32x4;
typedef __attribute__((ext_vector_type(16))) float f32x16;
typedef __hip_bfloat16 bf16;

__device__ __forceinline__ void load_lds16(const void* g, void* l) {
  __builtin_amdgcn_global_load_lds(
      (const __attribute__((address_space(1))) unsigned int*)g,
      (__attribute__((address_space(3))) unsigned int*)l, 16, 0, 0);
}

__device__ __forceinline__ unsigned short f2bf_bits(float f) {
  __hip_bfloat16 h = __float2bfloat16(f);
  return *reinterpret_cast<unsigned short*>(&h);
}
__device__ __forceinline__ unsigned pack2bf(float a, float b) {
  return (unsigned)f2bf_bits(a) | ((unsigned)f2bf_bits(b) << 16);
}
__device__ __forceinline__ unsigned cvt_pk_bf16(float a, float b) {
  unsigned r;
  asm("v_cvt_pk_bf16_f32 %0, %1, %2" : "=v"(r) : "v"(a), "v"(b));
  return r;
}

// ---------------- prep: x cvt + both W transposes, ONE launch ----------------
__global__ void prep_all(const float* __restrict__ x, bf16* __restrict__ xb,
                         const float* __restrict__ Wa, bf16* __restrict__ WTa,
                         const float* __restrict__ Wp, bf16* __restrict__ WTp) {
  __shared__ float tile[32][33];
  int bx = blockIdx.x;
  if (bx < 4096) {
    int i = bx * 256 + threadIdx.x;
    float4 v = reinterpret_cast<const float4*>(x)[i];
    ushort4 o;
    o.x = f2bf_bits(v.x); o.y = f2bf_bits(v.y);
    o.z = f2bf_bits(v.z); o.w = f2bf_bits(v.w);
    reinterpret_cast<ushort4*>(xb)[i] = o;
    return;
  }
  bx -= 4096;
  const float* W; bf16* WT; int N, tpr;
  if (bx < 3072) { W = Wa; WT = WTa; N = 3072; tpr = 96; }
  else           { W = Wp; WT = WTp; N = 1024; tpr = 32; bx -= 3072; }
  const int K = 1024;
  // tpr=96 is NOT a power of two -> true % and / (R13 bug)
  int n0 = (bx % tpr) * 32, k0 = (bx / tpr) * 32;
  int tx = threadIdx.x & 31, ty = threadIdx.x >> 5;   // 32 x 8
#pragma unroll
  for (int i = 0; i < 32; i += 8)
    tile[ty + i][tx] = W[(size_t)(k0 + ty + i) * N + n0 + tx];
  __syncthreads();
#pragma unroll
  for (int i = 0; i < 32; i += 8)
    WT[(size_t)(n0 + ty + i) * K + k0 + tx] = __float2bfloat16(tile[tx][ty + i]);
}

// ---------------- GEMM: C[M][N] = A[M][K] * BT[N][K]^T + bias ----------------
// R14-proven: dbuf LDS + counted vmcnt (T4) + XOR-swizzled staging/reads (T2).
template <int EPI>
__global__ __launch_bounds__(256, 2)
void gemm128(const bf16* __restrict__ A, const bf16* __restrict__ BT,
             const float* __restrict__ bias,
             bf16* __restrict__ Qo, bf16* __restrict__ Ko, bf16* __restrict__ Vo,
             float* __restrict__ Fo) {
  const int Kdim = 1024;
  __shared__ char smem[65536];   // buf b at b*32768: As 16KB | Bs 16KB
  const int tid = threadIdx.x;
  const int wid = tid >> 6, lane = tid & 63;
  const int m0 = blockIdx.x * 128;
  const int n0 = blockIdx.y * 128;
  const int wrow = (wid >> 1) * 64, wcol = (wid & 1) * 64;

  f32x4 acc[4][4];
#pragma unroll
  for (int rb = 0; rb < 4; ++rb)
#pragma unroll
    for (int cb = 0; cb < 4; ++cb)
      acc[rb][cb] = (f32x4){0.f, 0.f, 0.f, 0.f};

  const int lr = lane >> 3;
  const int cc = lane & 7;
  const int gc = (cc ^ lr) * 8;          // pre-swizzled source col (elems)
  const int fr = lane & 15;
  const int fk2 = (lane >> 4) * 16;      // fragment k-offset in bytes
  const int fswz = (fr & 7) << 4;        // read-side XOR

  auto stage = [&](int kt) {
    char* nb = smem + (kt & 1) * 32768;
#pragma unroll
    for (int t = 0; t < 4; ++t) {
      int i = wid * 4 + t;
      int row = i * 8 + lr;
      load_lds16(A + (size_t)(m0 + row) * Kdim + kt * 64 + gc, nb + i * 1024);
      load_lds16(BT + (size_t)(n0 + row) * Kdim + kt * 64 + gc,
                 nb + 16384 + i * 1024);
    }
  };

  stage(0);

  for (int kt = 0; kt < Kdim / 64; ++kt) {
    const char* Asc = smem + (kt & 1) * 32768;
    const char* Bsc = Asc + 16384;

    __builtin_amdgcn_s_barrier();
    __builtin_amdgcn_sched_barrier(0);

    if (kt + 1 < Kdim / 64) {
      stage(kt + 1);
      asm volatile("s_waitcnt vmcnt(8)" ::: "memory");
    } else {
      asm volatile("s_waitcnt vmcnt(0)" ::: "memory");
    }
    __builtin_amdgcn_sched_barrier(0);

    __builtin_amdgcn_s_barrier();
    __builtin_amdgcn_sched_barrier(0);

    short8 af[4][2], bf_[4][2];
#pragma unroll
    for (int rb = 0; rb < 4; ++rb)
#pragma unroll
      for (int kk = 0; kk < 2; ++kk) {
        af[rb][kk] = *(const short8*)(Asc + (wrow + rb * 16 + fr) * 128 +
                                      ((kk * 64 + fk2) ^ fswz));
        bf_[rb][kk] = *(const short8*)(Bsc + (wcol + rb * 16 + fr) * 128 +
                                       ((kk * 64 + fk2) ^ fswz));
      }
    __builtin_amdgcn_s_setprio(1);
#pragma unroll
    for (int rb = 0; rb < 4; ++rb)
#pragma unroll
      for (int cb = 0; cb < 4; ++cb)
#pragma unroll
        for (int kk = 0; kk < 2; ++kk)
          acc[rb][cb] = __builtin_amdgcn_mfma_f32_16x16x32_bf16(
              af[rb][kk], bf_[cb][kk], acc[rb][cb], 0, 0, 0);
    __builtin_amdgcn_s_setprio(0);
  }

  const int fg = (lane >> 4) * 4;
  float bv[4];
#pragma unroll
  for (int cb = 0; cb < 4; ++cb) bv[cb] = bias[n0 + wcol + cb * 16 + fr];

  if (EPI == 0) {
    __syncthreads();
    char* ep = smem + wid * 8192;
    const int ncol = n0 + wcol;
    const int part = ncol >> 10;
    const int h = (ncol & 1023) >> 6;
    const int b = m0 >> 11;
    const int s_base = (m0 + wrow) & 2047;
    const size_t hb = (size_t)(b * NH + h);

    if (part < 2) {
      const float qs = (part == 0) ? QSCALE : 1.f;
#pragma unroll
      for (int rb = 0; rb < 4; ++rb)
#pragma unroll
        for (int cb = 0; cb < 4; ++cb)
#pragma unroll
          for (int j = 0; j < 4; ++j) {
            int row = rb * 16 + fg + j;
            int colb = (cb * 16 + fr) * 2;
            *(unsigned short*)(ep + row * 128 + (colb ^ ((row & 7) << 4))) =
                f2bf_bits((acc[rb][cb][j] + bv[cb]) * qs);
          }
      bf16* dst = (part == 0 ? Qo : Ko) + hb * SEQ * HD;
#pragma unroll
      for (int p = 0; p < 8; ++p) {
        int row = p * 8 + lr;
        uint4 v = *(const uint4*)(ep + row * 128 + ((cc * 16) ^ ((row & 7) << 4)));
        *(uint4*)(dst + (size_t)(s_base + row) * HD + cc * 8) = v;
      }
    } else {
#pragma unroll
      for (int rb = 0; rb < 4; ++rb)
#pragma unroll
        for (int cb = 0; cb < 4; ++cb) {
          int cV = cb * 16 + fr;
          int r0 = (rb * 16 + fg) * 2;
          uint2 wv;
          wv.x = pack2bf(acc[rb][cb][0] + bv[cb], acc[rb][cb][1] + bv[cb]);
          wv.y = pack2bf(acc[rb][cb][2] + bv[cb], acc[rb][cb][3] + bv[cb]);
          *(uint2*)(ep + cV * 128 + (r0 ^ ((cV & 7) << 4))) = wv;
        }
      bf16* dstV = Vo + hb * HD * SEQ;
#pragma unroll
      for (int p = 0; p < 8; ++p) {
        int hd = p * 8 + lr;
        uint4 v = *(const uint4*)(ep + hd * 128 + ((cc * 16) ^ ((hd & 7) << 4)));
        *(uint4*)(dstV + (size_t)hd * SEQ + s_base + cc * 8) = v;
      }
    }
  } else {
#pragma unroll
    for (int rb = 0; rb < 4; ++rb) {
      int r0 = m0 + wrow + rb * 16 + fg;
#pragma unroll
      for (int cb = 0; cb < 4; ++cb) {
        int n = n0 + wcol + cb * 16 + fr;
#pragma unroll
        for (int j = 0; j < 4; ++j)
          Fo[(size_t)(r0 + j) * HID + n] = acc[rb][cb][j] + bv[cb];
      }
    }
  }
}

// ---------------- proj GEMM: tile 128x64 for 2x occupancy ----------------
// gemm128's BN=128 grid gives only 256 blocks = 1 block/CU = 1 wave/SIMD for
// the proj (N=1024). Tile 128x64 -> 512 blocks -> 2 resident/CU (LDS 48KB
// dbuf). Same proven schedule: T2 swizzle + two-barrier counted-vmcnt epoch
// (6 staging loads/wave -> vmcnt(6)). Per wave 64x32 output, acc[4][2].
__global__ __launch_bounds__(256, 2)
void gemm_proj(const bf16* __restrict__ A, const bf16* __restrict__ BT,
               const float* __restrict__ bias, float* __restrict__ Fo) {
  const int Kdim = 1024;
  __shared__ char smem[49152];   // buf b at b*24576: As 16KB | Bs 8KB
  const int tid = threadIdx.x;
  const int wid = tid >> 6, lane = tid & 63;
  const int m0 = blockIdx.x * 128;
  const int n0 = blockIdx.y * 64;
  const int wrow = (wid >> 1) * 64, wcol = (wid & 1) * 32;

  f32x4 acc[4][2];
#pragma unroll
  for (int rb = 0; rb < 4; ++rb)
#pragma unroll
    for (int cb = 0; cb < 2; ++cb)
      acc[rb][cb] = (f32x4){0.f, 0.f, 0.f, 0.f};

  const int lr = lane >> 3;
  const int cc = lane & 7;
  const int gc = (cc ^ lr) * 8;          // pre-swizzled source col (elems)
  const int fr = lane & 15;
  const int fk2 = (lane >> 4) * 16;      // fragment k-offset in bytes
  const int fswz = (fr & 7) << 4;        // read-side XOR

  // 24 chunks of 1KB (8 rows x 128B): 0..15 = A (128 rows), 16..23 = B (64)
  auto stage = [&](int kt) {
    char* nb = smem + (kt & 1) * 24576;
#pragma unroll
    for (int t = 0; t < 6; ++t) {
      int c = wid * 6 + t;
      if (c < 16) {
        int row = c * 8 + lr;
        load_lds16(A + (size_t)(m0 + row) * Kdim + kt * 64 + gc, nb + c * 1024);
      } else {
        int row = (c - 16) * 8 + lr;
        load_lds16(BT + (size_t)(n0 + row) * Kdim + kt * 64 + gc,
                   nb + 16384 + (c - 16) * 1024);
      }
    }
  };

  stage(0);

  for (int kt = 0; kt < Kdim / 64; ++kt) {
    const char* Asc = smem + (kt & 1) * 24576;
    const char* Bsc = Asc + 16384;

    __builtin_amdgcn_s_barrier();
    __builtin_amdgcn_sched_barrier(0);

    if (kt + 1 < Kdim / 64) {
      stage(kt + 1);                     // 6 VMEM ops, stay in flight
      asm volatile("s_waitcnt vmcnt(6)" ::: "memory");  // own stage(kt) done
    } else {
      asm volatile("s_waitcnt vmcnt(0)" ::: "memory");  // tail: full drain
    }
    __builtin_amdgcn_sched_barrier(0);

    __builtin_amdgcn_s_barrier();
    __builtin_amdgcn_sched_barrier(0);

    short8 af[4][2], bf_[2][2];
#pragma unroll
    for (int rb = 0; rb < 4; ++rb)
#pragma unroll
      for (int kk = 0; kk < 2; ++kk)
        af[rb][kk] = *(const short8*)(Asc + (wrow + rb * 16 + fr) * 128 +
                                      ((kk * 64 + fk2) ^ fswz));
#pragma unroll
    for (int cb = 0; cb < 2; ++cb)
#pragma unroll
      for (int kk = 0; kk < 2; ++kk)
        bf_[cb][kk] = *(const short8*)(Bsc + (wcol + cb * 16 + fr) * 128 +
                                       ((kk * 64 + fk2) ^ fswz));
    __builtin_amdgcn_s_setprio(1);
#pragma unroll
    for (int rb = 0; rb < 4; ++rb)
#pragma unroll
      for (int cb = 0; cb < 2; ++cb)
#pragma unroll
        for (int kk = 0; kk < 2; ++kk)
          acc[rb][cb] = __builtin_amdgcn_mfma_f32_16x16x32_bf16(
              af[rb][kk], bf_[cb][kk], acc[rb][cb], 0, 0, 0);
    __builtin_amdgcn_s_setprio(0);
  }

  const int fg = (lane >> 4) * 4;
  float bv[2];
#pragma unroll
  for (int cb = 0; cb < 2; ++cb) bv[cb] = bias[n0 + wcol + cb * 16 + fr];

#pragma unroll
  for (int rb = 0; rb < 4; ++rb) {
    int r0 = m0 + wrow + rb * 16 + fg;
#pragma unroll
    for (int cb = 0; cb < 2; ++cb) {
      int n = n0 + wcol + cb * 16 + fr;
#pragma unroll
      for (int j = 0; j < 4; ++j)
        Fo[(size_t)(r0 + j) * HID + n] = acc[rb][cb][j] + bv[cb];
    }
  }
}

// ---------------- causal flash attention, swapped-operand 32x32 ----------------
// R15/R18 best-verified: R10 schedule + fused-pair software pipeline (qkA,qkB,
// expA,pvA,expB,pvB) + permlane32_swap P-exchange + fixed-zero-max softmax.
__global__ __launch_bounds__(256, 2)
void attn_kernel(const bf16* __restrict__ Q, const bf16* __restrict__ K,
                 const bf16* __restrict__ VT, bf16* __restrict__ ctx) {
  __shared__ char smem[65536];  // buf b at b*32768: {K0,V0,K1,V1} x 8KB
  const int tid = threadIdx.x, wid = tid >> 6, lane = tid & 63;
  const int idx = blockIdx.x;
  const int qt = (idx < 256) ? (15 - (idx >> 5)) : ((idx - 256) >> 5);
  const int bh = idx & 31;
  const int b = bh >> 4, h = bh & 15;
  const size_t base = (size_t)bh * SEQ * HD;
  const int q0 = qt * 128 + wid * 32;

  const int fr = lane & 31, hi = lane >> 5;
  const int lr = lane >> 3;              // 0..7
  const int cc = lane & 7;
  const int qg = q0 + fr;
  const int gc = (cc ^ lr) * 8;          // pre-swizzled source chunk

  short8 qf[4];
  const bf16* qp = Q + base + (size_t)qg * HD;
#pragma unroll
  for (int kc = 0; kc < 4; ++kc)
    qf[kc] = *(const short8*)(qp + kc * 16 + hi * 8);

  f32x16 oa[2], ob[2];
#pragma unroll
  for (int da = 0; da < 2; ++da)
#pragma unroll
    for (int r = 0; r < 16; ++r) { oa[da][r] = 0.f; ob[da][r] = 0.f; }
  float lpart = 0.f;

  // stage one 128-kv pair (8 gload_lds per wave)
  auto stage_pair = [&](int jp) {
    char* nb = smem + (jp & 1) * 32768;
    const int nv = jp * 128;
#pragma unroll
    for (int u = 0; u < 2; ++u)
#pragma unroll
      for (int t = 0; t < 2; ++t) {
        int i = wid * 2 + t;
        load_lds16(K + base + (size_t)(nv + u * 64 + i * 8 + lr) * HD + gc,
                   nb + u * 16384 + i * 1024);
        load_lds16(VT + base + (size_t)(i * 8 + lr) * SEQ + nv + u * 64 + gc,
                   nb + u * 16384 + 8192 + i * 1024);
      }
  };

  // QK for one 64-kv tile -> sa
  auto qk_tile = [&](const char* sb_t, f32x16 (&sa)[2]) {
    __builtin_amdgcn_s_setprio(1);
#pragma unroll
    for (int kb = 0; kb < 2; ++kb) {
#pragma unroll
      for (int r = 0; r < 16; ++r) sa[kb][r] = 0.f;
      const int row = kb * 32 + fr;
      const int swz = (row & 7) << 4;
#pragma unroll
      for (int kc = 0; kc < 4; ++kc) {
        short8 kf = *(const short8*)(sb_t + row * 128 + ((kc * 32 + hi * 16) ^ swz));
        sa[kb] = __builtin_amdgcn_mfma_f32_32x32x16_bf16(kf, qf[kc], sa[kb], 0, 0, 0);
      }
    }
    __builtin_amdgcn_s_setprio(0);
  };

  // mask + exp2 + pack -> pfr (P fragments for PV B-operand)
  auto sm_tile = [&](f32x16 (&sa)[2], int kv0, short8 (&pfr)[4]) {
    if (kv0 + 63 > q0) {                 // causal mask, boundary tiles only
#pragma unroll
      for (int kb = 0; kb < 2; ++kb)
#pragma unroll
        for (int r = 0; r < 16; ++r) {
          int kvg = kv0 + kb * 32 + (r & 3) + 8 * (r >> 2) + 4 * hi;
          sa[kb][r] = (kvg > qg) ? -1e30f : sa[kb][r];
        }
    }

    float s0 = 0.f, s1 = 0.f, s2 = 0.f, s3 = 0.f;
#pragma unroll
    for (int kb = 0; kb < 2; ++kb)
#pragma unroll
      for (int r = 0; r < 16; ++r) {
        float e = __builtin_exp2f(sa[kb][r]);
        sa[kb][r] = e;
        if ((r & 3) == 0)      s0 += e;
        else if ((r & 3) == 1) s1 += e;
        else if ((r & 3) == 2) s2 += e;
        else                   s3 += e;
      }
    lpart += (s0 + s1) + (s2 + s3);

    // pk[kb][i] holds kv = kb*32 + 8*(i>>1) + 2*(i&1) + 4*hi + {0,1};
    // PV word w of slice ks needs kv = ks*16 + hi*8 + 2w + {0,1}.
    unsigned pk[2][8];
#pragma unroll
    for (int kb = 0; kb < 2; ++kb)
#pragma unroll
      for (int i = 0; i < 8; ++i)
        pk[kb][i] = cvt_pk_bf16(sa[kb][2 * i], sa[kb][2 * i + 1]);

#pragma unroll
    for (int ks = 0; ks < 4; ++ks) {
      const int kb = ks >> 1, g = (ks & 1) * 4;
      auto r0 = __builtin_amdgcn_permlane32_swap((int)pk[kb][g + 0],
                                                 (int)pk[kb][g + 2], false, false);
      auto r1 = __builtin_amdgcn_permlane32_swap((int)pk[kb][g + 1],
                                                 (int)pk[kb][g + 3], false, false);
      union { unsigned u[4]; short8 s; } pf;
      pf.u[0] = (unsigned)r0[0]; pf.u[1] = (unsigned)r1[0];
      pf.u[2] = (unsigned)r0[1]; pf.u[3] = (unsigned)r1[1];
      pfr[ks] = pf.s;
    }
  };

  // PV for one tile
  auto pv_tile = [&](const char* sb_t, short8 (&pfr)[4], f32x16 (&oc)[2]) {
    __builtin_amdgcn_s_setprio(1);
#pragma unroll
    for (int da = 0; da < 2; ++da) {
      const int row = da * 32 + fr;
      const int swz = (row & 7) << 4;
#pragma unroll
      for (int ks = 0; ks < 4; ++ks) {
        short8 vf = *(const short8*)(sb_t + 8192 + row * 128 +
                                     ((ks * 32 + hi * 16) ^ swz));
        oc[da] = __builtin_amdgcn_mfma_f32_32x32x16_bf16(vf, pfr[ks], oc[da], 0, 0, 0);
      }
    }
    __builtin_amdgcn_s_setprio(0);
  };

  const int npair = qt + 1;              // 128 kv per pair

  stage_pair(0);

  for (int j = 0; j < npair; ++j) {
    char* sb = smem + (j & 1) * 32768;

    // barrier 1: all waves done computing pair j-1 -> buf (j+1)&1 reusable
    __builtin_amdgcn_s_barrier();
    __builtin_amdgcn_sched_barrier(0);

    if (j + 1 < npair) {
      stage_pair(j + 1);                 // 8 VMEM ops, stay in flight
      asm volatile("s_waitcnt vmcnt(8)" ::: "memory");  // own stage(j) done
    } else {
      asm volatile("s_waitcnt vmcnt(0)" ::: "memory");  // tail: full drain
    }
    __builtin_amdgcn_sched_barrier(0);

    // barrier 2: all waves' stage(j) loads have landed in LDS
    __builtin_amdgcn_s_barrier();
    __builtin_amdgcn_sched_barrier(0);

    const int kv0 = j * 128;
    if (kv0 + 64 <= q0 + 31) {
      // fused pair: qkA, qkB (fills A's MFMA tail), then A's softmax+PV,
      // then B's softmax+PV (expB interleaves with pvA on separate pipes)
      f32x16 saA[2], saB[2];
      short8 pfrA[4], pfrB[4];
      qk_tile(sb, saA);
      qk_tile(sb + 16384, saB);
      sm_tile(saA, kv0, pfrA);
      pv_tile(sb, pfrA, oa);
      sm_tile(saB, kv0 + 64, pfrB);
      pv_tile(sb + 16384, pfrB, ob);
    } else if (kv0 <= q0 + 31) {
      // boundary: only tile A causally valid for this wave
      f32x16 saA[2];
      short8 pfrA[4];
      qk_tile(sb, saA);
      sm_tile(saA, kv0, pfrA);
      pv_tile(sb, pfrA, oa);
    }
  }

  // ---------------- epilogue: per-wave LDS transpose, coalesced store ----------------
  const float lrun = lpart + __shfl_xor(lpart, 32);
  const float inv = 1.f / lrun;
  char* ep = smem + wid * 4096;
#pragma unroll
  for (int da = 0; da < 2; ++da)
#pragma unroll
    for (int rg = 0; rg < 4; ++rg) {
      int d0 = da * 64 + rg * 16 + hi * 8;
      float v0 = (oa[da][rg * 4 + 0] + ob[da][rg * 4 + 0]) * inv;
      float v1 = (oa[da][rg * 4 + 1] + ob[da][rg * 4 + 1]) * inv;
      float v2 = (oa[da][rg * 4 + 2] + ob[da][rg * 4 + 2]) * inv;
      float v3 = (oa[da][rg * 4 + 3] + ob[da][rg * 4 + 3]) * inv;
      uint2 wv; wv.x = pack2bf(v0, v1); wv.y = pack2bf(v2, v3);
      *(uint2*)(ep + fr * 128 + (d0 ^ ((fr & 7) << 4))) = wv;
    }
  // per-wave data only -> same-wave lgkmcnt ordering suffices
#pragma unroll
  for (int p = 0; p < 4; ++p) {
    int qr = p * 8 + lr;
    uint4 v = *(const uint4*)(ep + qr * 128 + ((cc * 16) ^ ((qr & 7) << 4)));
    int s = q0 + qr;
    *(uint4*)(ctx + (size_t)(b * SEQ + s) * HID + h * 64 + cc * 8) = v;
  }
}

// ---------------- launch ----------------
extern "C" void kernel_launch(void* const* d_in, const int* in_sizes, int n_in,
                              void* d_out, int out_size, void* d_ws, size_t ws_size,
                              hipStream_t stream) {
  const float* x      = (const float*)d_in[0];
  const float* W_attn = (const float*)d_in[1];
  const float* b_attn = (const float*)d_in[2];
  const float* W_proj = (const float*)d_in[3];
  const float* b_proj = (const float*)d_in[4];
  float* out = (float*)d_out;

  char* ws = (char*)d_ws;
  const size_t MB = 1u << 20;
  bf16* xb   = (bf16*)(ws + 0);
  bf16* WTa  = (bf16*)(ws + 8 * MB);
  bf16* WTp  = (bf16*)(ws + 14 * MB);
  bf16* Qw   = (bf16*)(ws + 16 * MB);
  bf16* Kw   = (bf16*)(ws + 24 * MB);
  bf16* VTw  = (bf16*)(ws + 32 * MB);
  bf16* ctxb = (bf16*)(ws + 40 * MB);

  prep_all<<<dim3(8192), 256, 0, stream>>>(x, xb, W_attn, WTa, W_proj, WTp);

  gemm128<0><<<dim3(M_TOT / 128, 3 * HID / 128), 256, 0, stream>>>(
      xb, WTa, b_attn, Qw, Kw, VTw, nullptr);

  attn_kernel<<<dim3(512), 256, 0, stream>>>(Qw, Kw, VTw, ctxb);

  gemm_proj<<<dim3(M_TOT / 128, HID / 64), 256, 0, stream>>>(
      ctxb, WTp, b_proj, out);
}

// Round 24
// 97.311 us; speedup vs baseline: 1.0164x; 1.0164x over previous
//
#include <hip/hip_runtime.h>
#include <hip/hip_bf16.h>
#include <stdint.h>

#define HID 1024
#define NH 16
#define HD 64
#define SEQ 2048
#define BATCH 2
#define M_TOT 4096
#define QSCALE 0.18033688011112042f  /* 0.125 * log2(e) */

typedef __attribute__((ext_vector_type(8))) short short8;
typedef __attribute__((ext_vector_type(4))) float f32x4;
typedef __attribute__((ext_vector_type(16))) float f32x16;
typedef __hip_bfloat16 bf16;

__device__ __forceinline__ void load_lds16(const void* g, void* l) {
  __builtin_amdgcn_global_load_lds(
      (const __attribute__((address_space(1))) unsigned int*)g,
      (__attribute__((address_space(3))) unsigned int*)l, 16, 0, 0);
}

__device__ __forceinline__ unsigned short f2bf_bits(float f) {
  __hip_bfloat16 h = __float2bfloat16(f);
  return *reinterpret_cast<unsigned short*>(&h);
}
__device__ __forceinline__ unsigned pack2bf(float a, float b) {
  return (unsigned)f2bf_bits(a) | ((unsigned)f2bf_bits(b) << 16);
}
__device__ __forceinline__ unsigned cvt_pk_bf16(float a, float b) {
  unsigned r;
  asm("v_cvt_pk_bf16_f32 %0, %1, %2" : "=v"(r) : "v"(a), "v"(b));
  return r;
}

// ---------------- prep: x cvt + both W transposes, ONE launch ----------------
__global__ void prep_all(const float* __restrict__ x, bf16* __restrict__ xb,
                         const float* __restrict__ Wa, bf16* __restrict__ WTa,
                         const float* __restrict__ Wp, bf16* __restrict__ WTp) {
  __shared__ float tile[32][33];
  int bx = blockIdx.x;
  if (bx < 4096) {
    int i = bx * 256 + threadIdx.x;
    float4 v = reinterpret_cast<const float4*>(x)[i];
    ushort4 o;
    o.x = f2bf_bits(v.x); o.y = f2bf_bits(v.y);
    o.z = f2bf_bits(v.z); o.w = f2bf_bits(v.w);
    reinterpret_cast<ushort4*>(xb)[i] = o;
    return;
  }
  bx -= 4096;
  const float* W; bf16* WT; int N, tpr;
  if (bx < 3072) { W = Wa; WT = WTa; N = 3072; tpr = 96; }
  else           { W = Wp; WT = WTp; N = 1024; tpr = 32; bx -= 3072; }
  const int K = 1024;
  // tpr=96 is NOT a power of two -> true % and / (R13 bug)
  int n0 = (bx % tpr) * 32, k0 = (bx / tpr) * 32;
  int tx = threadIdx.x & 31, ty = threadIdx.x >> 5;   // 32 x 8
#pragma unroll
  for (int i = 0; i < 32; i += 8)
    tile[ty + i][tx] = W[(size_t)(k0 + ty + i) * N + n0 + tx];
  __syncthreads();
#pragma unroll
  for (int i = 0; i < 32; i += 8)
    WT[(size_t)(n0 + ty + i) * K + k0 + tx] = __float2bfloat16(tile[tx][ty + i]);
}

// ---------------- GEMM: C[M][N] = A[M][K] * BT[N][K]^T + bias ----------------
// R14-proven: dbuf LDS + counted vmcnt (T4) + XOR-swizzled staging/reads (T2).
template <int EPI>
__global__ __launch_bounds__(256, 2)
void gemm128(const bf16* __restrict__ A, const bf16* __restrict__ BT,
             const float* __restrict__ bias,
             bf16* __restrict__ Qo, bf16* __restrict__ Ko, bf16* __restrict__ Vo,
             float* __restrict__ Fo) {
  const int Kdim = 1024;
  __shared__ char smem[65536];   // buf b at b*32768: As 16KB | Bs 16KB
  const int tid = threadIdx.x;
  const int wid = tid >> 6, lane = tid & 63;
  const int m0 = blockIdx.x * 128;
  const int n0 = blockIdx.y * 128;
  const int wrow = (wid >> 1) * 64, wcol = (wid & 1) * 64;

  f32x4 acc[4][4];
#pragma unroll
  for (int rb = 0; rb < 4; ++rb)
#pragma unroll
    for (int cb = 0; cb < 4; ++cb)
      acc[rb][cb] = (f32x4){0.f, 0.f, 0.f, 0.f};

  const int lr = lane >> 3;
  const int cc = lane & 7;
  const int gc = (cc ^ lr) * 8;          // pre-swizzled source col (elems)
  const int fr = lane & 15;
  const int fk2 = (lane >> 4) * 16;      // fragment k-offset in bytes
  const int fswz = (fr & 7) << 4;        // read-side XOR

  auto stage = [&](int kt) {
    char* nb = smem + (kt & 1) * 32768;
#pragma unroll
    for (int t = 0; t < 4; ++t) {
      int i = wid * 4 + t;
      int row = i * 8 + lr;
      load_lds16(A + (size_t)(m0 + row) * Kdim + kt * 64 + gc, nb + i * 1024);
      load_lds16(BT + (size_t)(n0 + row) * Kdim + kt * 64 + gc,
                 nb + 16384 + i * 1024);
    }
  };

  stage(0);

  for (int kt = 0; kt < Kdim / 64; ++kt) {
    const char* Asc = smem + (kt & 1) * 32768;
    const char* Bsc = Asc + 16384;

    __builtin_amdgcn_s_barrier();
    __builtin_amdgcn_sched_barrier(0);

    if (kt + 1 < Kdim / 64) {
      stage(kt + 1);
      asm volatile("s_waitcnt vmcnt(8)" ::: "memory");
    } else {
      asm volatile("s_waitcnt vmcnt(0)" ::: "memory");
    }
    __builtin_amdgcn_sched_barrier(0);

    __builtin_amdgcn_s_barrier();
    __builtin_amdgcn_sched_barrier(0);

    short8 af[4][2], bf_[4][2];
#pragma unroll
    for (int rb = 0; rb < 4; ++rb)
#pragma unroll
      for (int kk = 0; kk < 2; ++kk) {
        af[rb][kk] = *(const short8*)(Asc + (wrow + rb * 16 + fr) * 128 +
                                      ((kk * 64 + fk2) ^ fswz));
        bf_[rb][kk] = *(const short8*)(Bsc + (wcol + rb * 16 + fr) * 128 +
                                       ((kk * 64 + fk2) ^ fswz));
      }
    __builtin_amdgcn_s_setprio(1);
#pragma unroll
    for (int rb = 0; rb < 4; ++rb)
#pragma unroll
      for (int cb = 0; cb < 4; ++cb)
#pragma unroll
        for (int kk = 0; kk < 2; ++kk)
          acc[rb][cb] = __builtin_amdgcn_mfma_f32_16x16x32_bf16(
              af[rb][kk], bf_[cb][kk], acc[rb][cb], 0, 0, 0);
    __builtin_amdgcn_s_setprio(0);
  }

  const int fg = (lane >> 4) * 4;
  float bv[4];
#pragma unroll
  for (int cb = 0; cb < 4; ++cb) bv[cb] = bias[n0 + wcol + cb * 16 + fr];

  if (EPI == 0) {
    __syncthreads();
    char* ep = smem + wid * 8192;
    const int ncol = n0 + wcol;
    const int part = ncol >> 10;
    const int h = (ncol & 1023) >> 6;
    const int b = m0 >> 11;
    const int s_base = (m0 + wrow) & 2047;
    const size_t hb = (size_t)(b * NH + h);

    if (part < 2) {
      const float qs = (part == 0) ? QSCALE : 1.f;
#pragma unroll
      for (int rb = 0; rb < 4; ++rb)
#pragma unroll
        for (int cb = 0; cb < 4; ++cb)
#pragma unroll
          for (int j = 0; j < 4; ++j) {
            int row = rb * 16 + fg + j;
            int colb = (cb * 16 + fr) * 2;
            *(unsigned short*)(ep + row * 128 + (colb ^ ((row & 7) << 4))) =
                f2bf_bits((acc[rb][cb][j] + bv[cb]) * qs);
          }
      bf16* dst = (part == 0 ? Qo : Ko) + hb * SEQ * HD;
#pragma unroll
      for (int p = 0; p < 8; ++p) {
        int row = p * 8 + lr;
        uint4 v = *(const uint4*)(ep + row * 128 + ((cc * 16) ^ ((row & 7) << 4)));
        *(uint4*)(dst + (size_t)(s_base + row) * HD + cc * 8) = v;
      }
    } else {
#pragma unroll
      for (int rb = 0; rb < 4; ++rb)
#pragma unroll
        for (int cb = 0; cb < 4; ++cb) {
          int cV = cb * 16 + fr;
          int r0 = (rb * 16 + fg) * 2;
          uint2 wv;
          wv.x = pack2bf(acc[rb][cb][0] + bv[cb], acc[rb][cb][1] + bv[cb]);
          wv.y = pack2bf(acc[rb][cb][2] + bv[cb], acc[rb][cb][3] + bv[cb]);
          *(uint2*)(ep + cV * 128 + (r0 ^ ((cV & 7) << 4))) = wv;
        }
      bf16* dstV = Vo + hb * HD * SEQ;
#pragma unroll
      for (int p = 0; p < 8; ++p) {
        int hd = p * 8 + lr;
        uint4 v = *(const uint4*)(ep + hd * 128 + ((cc * 16) ^ ((hd & 7) << 4)));
        *(uint4*)(dstV + (size_t)hd * SEQ + s_base + cc * 8) = v;
      }
    }
  } else {
#pragma unroll
    for (int rb = 0; rb < 4; ++rb) {
      int r0 = m0 + wrow + rb * 16 + fg;
#pragma unroll
      for (int cb = 0; cb < 4; ++cb) {
        int n = n0 + wcol + cb * 16 + fr;
#pragma unroll
        for (int j = 0; j < 4; ++j)
          Fo[(size_t)(r0 + j) * HID + n] = acc[rb][cb][j] + bv[cb];
      }
    }
  }
}

// ---------------- causal flash attention, swapped-operand 32x32 ----------------
// R15/R18 best-verified: R10 schedule + fused-pair software pipeline (qkA,qkB,
// expA,pvA,expB,pvB) + permlane32_swap P-exchange + fixed-zero-max softmax.
__global__ __launch_bounds__(256, 2)
void attn_kernel(const bf16* __restrict__ Q, const bf16* __restrict__ K,
                 const bf16* __restrict__ VT, bf16* __restrict__ ctx) {
  __shared__ char smem[65536];  // buf b at b*32768: {K0,V0,K1,V1} x 8KB
  const int tid = threadIdx.x, wid = tid >> 6, lane = tid & 63;
  const int idx = blockIdx.x;
  const int qt = (idx < 256) ? (15 - (idx >> 5)) : ((idx - 256) >> 5);
  const int bh = idx & 31;
  const int b = bh >> 4, h = bh & 15;
  const size_t base = (size_t)bh * SEQ * HD;
  const int q0 = qt * 128 + wid * 32;

  const int fr = lane & 31, hi = lane >> 5;
  const int lr = lane >> 3;              // 0..7
  const int cc = lane & 7;
  const int qg = q0 + fr;
  const int gc = (cc ^ lr) * 8;          // pre-swizzled source chunk

  short8 qf[4];
  const bf16* qp = Q + base + (size_t)qg * HD;
#pragma unroll
  for (int kc = 0; kc < 4; ++kc)
    qf[kc] = *(const short8*)(qp + kc * 16 + hi * 8);

  f32x16 oa[2], ob[2];
#pragma unroll
  for (int da = 0; da < 2; ++da)
#pragma unroll
    for (int r = 0; r < 16; ++r) { oa[da][r] = 0.f; ob[da][r] = 0.f; }
  float lpart = 0.f;

  // stage one 128-kv pair (8 gload_lds per wave)
  auto stage_pair = [&](int jp) {
    char* nb = smem + (jp & 1) * 32768;
    const int nv = jp * 128;
#pragma unroll
    for (int u = 0; u < 2; ++u)
#pragma unroll
      for (int t = 0; t < 2; ++t) {
        int i = wid * 2 + t;
        load_lds16(K + base + (size_t)(nv + u * 64 + i * 8 + lr) * HD + gc,
                   nb + u * 16384 + i * 1024);
        load_lds16(VT + base + (size_t)(i * 8 + lr) * SEQ + nv + u * 64 + gc,
                   nb + u * 16384 + 8192 + i * 1024);
      }
  };

  // QK for one 64-kv tile -> sa
  auto qk_tile = [&](const char* sb_t, f32x16 (&sa)[2]) {
    __builtin_amdgcn_s_setprio(1);
#pragma unroll
    for (int kb = 0; kb < 2; ++kb) {
#pragma unroll
      for (int r = 0; r < 16; ++r) sa[kb][r] = 0.f;
      const int row = kb * 32 + fr;
      const int swz = (row & 7) << 4;
#pragma unroll
      for (int kc = 0; kc < 4; ++kc) {
        short8 kf = *(const short8*)(sb_t + row * 128 + ((kc * 32 + hi * 16) ^ swz));
        sa[kb] = __builtin_amdgcn_mfma_f32_32x32x16_bf16(kf, qf[kc], sa[kb], 0, 0, 0);
      }
    }
    __builtin_amdgcn_s_setprio(0);
  };

  // mask + exp2 + pack -> pfr (P fragments for PV B-operand)
  auto sm_tile = [&](f32x16 (&sa)[2], int kv0, short8 (&pfr)[4]) {
    if (kv0 + 63 > q0) {                 // causal mask, boundary tiles only
#pragma unroll
      for (int kb = 0; kb < 2; ++kb)
#pragma unroll
        for (int r = 0; r < 16; ++r) {
          int kvg = kv0 + kb * 32 + (r & 3) + 8 * (r >> 2) + 4 * hi;
          sa[kb][r] = (kvg > qg) ? -1e30f : sa[kb][r];
        }
    }

    float s0 = 0.f, s1 = 0.f, s2 = 0.f, s3 = 0.f;
#pragma unroll
    for (int kb = 0; kb < 2; ++kb)
#pragma unroll
      for (int r = 0; r < 16; ++r) {
        float e = __builtin_exp2f(sa[kb][r]);
        sa[kb][r] = e;
        if ((r & 3) == 0)      s0 += e;
        else if ((r & 3) == 1) s1 += e;
        else if ((r & 3) == 2) s2 += e;
        else                   s3 += e;
      }
    lpart += (s0 + s1) + (s2 + s3);

    // pk[kb][i] holds kv = kb*32 + 8*(i>>1) + 2*(i&1) + 4*hi + {0,1};
    // PV word w of slice ks needs kv = ks*16 + hi*8 + 2w + {0,1}.
    unsigned pk[2][8];
#pragma unroll
    for (int kb = 0; kb < 2; ++kb)
#pragma unroll
      for (int i = 0; i < 8; ++i)
        pk[kb][i] = cvt_pk_bf16(sa[kb][2 * i], sa[kb][2 * i + 1]);

#pragma unroll
    for (int ks = 0; ks < 4; ++ks) {
      const int kb = ks >> 1, g = (ks & 1) * 4;
      auto r0 = __builtin_amdgcn_permlane32_swap((int)pk[kb][g + 0],
                                                 (int)pk[kb][g + 2], false, false);
      auto r1 = __builtin_amdgcn_permlane32_swap((int)pk[kb][g + 1],
                                                 (int)pk[kb][g + 3], false, false);
      union { unsigned u[4]; short8 s; } pf;
      pf.u[0] = (unsigned)r0[0]; pf.u[1] = (unsigned)r1[0];
      pf.u[2] = (unsigned)r0[1]; pf.u[3] = (unsigned)r1[1];
      pfr[ks] = pf.s;
    }
  };

  // PV for one tile
  auto pv_tile = [&](const char* sb_t, short8 (&pfr)[4], f32x16 (&oc)[2]) {
    __builtin_amdgcn_s_setprio(1);
#pragma unroll
    for (int da = 0; da < 2; ++da) {
      const int row = da * 32 + fr;
      const int swz = (row & 7) << 4;
#pragma unroll
      for (int ks = 0; ks < 4; ++ks) {
        short8 vf = *(const short8*)(sb_t + 8192 + row * 128 +
                                     ((ks * 32 + hi * 16) ^ swz));
        oc[da] = __builtin_amdgcn_mfma_f32_32x32x16_bf16(vf, pfr[ks], oc[da], 0, 0, 0);
      }
    }
    __builtin_amdgcn_s_setprio(0);
  };

  const int npair = qt + 1;              // 128 kv per pair

  stage_pair(0);

  for (int j = 0; j < npair; ++j) {
    char* sb = smem + (j & 1) * 32768;

    // barrier 1: all waves done computing pair j-1 -> buf (j+1)&1 reusable
    __builtin_amdgcn_s_barrier();
    __builtin_amdgcn_sched_barrier(0);

    if (j + 1 < npair) {
      stage_pair(j + 1);                 // 8 VMEM ops, stay in flight
      asm volatile("s_waitcnt vmcnt(8)" ::: "memory");  // own stage(j) done
    } else {
      asm volatile("s_waitcnt vmcnt(0)" ::: "memory");  // tail: full drain
    }
    __builtin_amdgcn_sched_barrier(0);

    // barrier 2: all waves' stage(j) loads have landed in LDS
    __builtin_amdgcn_s_barrier();
    __builtin_amdgcn_sched_barrier(0);

    const int kv0 = j * 128;
    if (kv0 + 64 <= q0 + 31) {
      // fused pair: qkA, qkB (fills A's MFMA tail), then A's softmax+PV,
      // then B's softmax+PV (expB interleaves with pvA on separate pipes)
      f32x16 saA[2], saB[2];
      short8 pfrA[4], pfrB[4];
      qk_tile(sb, saA);
      qk_tile(sb + 16384, saB);
      sm_tile(saA, kv0, pfrA);
      pv_tile(sb, pfrA, oa);
      sm_tile(saB, kv0 + 64, pfrB);
      pv_tile(sb + 16384, pfrB, ob);
    } else if (kv0 <= q0 + 31) {
      // boundary: only tile A causally valid for this wave
      f32x16 saA[2];
      short8 pfrA[4];
      qk_tile(sb, saA);
      sm_tile(saA, kv0, pfrA);
      pv_tile(sb, pfrA, oa);
    }
  }

  // ---------------- epilogue: per-wave LDS transpose, coalesced store ----------------
  const float lrun = lpart + __shfl_xor(lpart, 32);
  const float inv = 1.f / lrun;
  char* ep = smem + wid * 4096;
#pragma unroll
  for (int da = 0; da < 2; ++da)
#pragma unroll
    for (int rg = 0; rg < 4; ++rg) {
      int d0 = da * 64 + rg * 16 + hi * 8;
      float v0 = (oa[da][rg * 4 + 0] + ob[da][rg * 4 + 0]) * inv;
      float v1 = (oa[da][rg * 4 + 1] + ob[da][rg * 4 + 1]) * inv;
      float v2 = (oa[da][rg * 4 + 2] + ob[da][rg * 4 + 2]) * inv;
      float v3 = (oa[da][rg * 4 + 3] + ob[da][rg * 4 + 3]) * inv;
      uint2 wv; wv.x = pack2bf(v0, v1); wv.y = pack2bf(v2, v3);
      *(uint2*)(ep + fr * 128 + (d0 ^ ((fr & 7) << 4))) = wv;
    }
  // per-wave data only -> same-wave lgkmcnt ordering suffices
#pragma unroll
  for (int p = 0; p < 4; ++p) {
    int qr = p * 8 + lr;
    uint4 v = *(const uint4*)(ep + qr * 128 + ((cc * 16) ^ ((qr & 7) << 4)));
    int s = q0 + qr;
    *(uint4*)(ctx + (size_t)(b * SEQ + s) * HID + h * 64 + cc * 8) = v;
  }
}

// ---------------- launch ----------------
extern "C" void kernel_launch(void* const* d_in, const int* in_sizes, int n_in,
                              void* d_out, int out_size, void* d_ws, size_t ws_size,
                              hipStream_t stream) {
  const float* x      = (const float*)d_in[0];
  const float* W_attn = (const float*)d_in[1];
  const float* b_attn = (const float*)d_in[2];
  const float* W_proj = (const float*)d_in[3];
  const float* b_proj = (const float*)d_in[4];
  float* out = (float*)d_out;

  char* ws = (char*)d_ws;
  const size_t MB = 1u << 20;
  bf16* xb   = (bf16*)(ws + 0);
  bf16* WTa  = (bf16*)(ws + 8 * MB);
  bf16* WTp  = (bf16*)(ws + 14 * MB);
  bf16* Qw   = (bf16*)(ws + 16 * MB);
  bf16* Kw   = (bf16*)(ws + 24 * MB);
  bf16* VTw  = (bf16*)(ws + 32 * MB);
  bf16* ctxb = (bf16*)(ws + 40 * MB);

  prep_all<<<dim3(8192), 256, 0, stream>>>(x, xb, W_attn, WTa, W_proj, WTp);

  gemm128<0><<<dim3(M_TOT / 128, 3 * HID / 128), 256, 0, stream>>>(
      xb, WTa, b_attn, Qw, Kw, VTw, nullptr);

  attn_kernel<<<dim3(512), 256, 0, stream>>>(Qw, Kw, VTw, ctxb);

  gemm128<1><<<dim3(M_TOT / 128, HID / 128), 256, 0, stream>>>(
      ctxb, WTp, b_proj, nullptr, nullptr, nullptr, out);
}